// Round 5
// baseline (5457.874 us; speedup 1.0000x reference)
//
#include <hip/hip_runtime.h>
#include <cstdint>
#include <cstddef>

namespace {

constexpr int NN   = 200000;   // nodes
constexpr int NE   = 800000;   // edges
constexpr int NG   = 4096;     // graphs
constexpr int MAXD = 5;

constexpr int BM = 64;
constexpr int BN = 128;
constexpr int KT = 32;
constexpr int NBLK  = (NN + BM - 1) / BM + 6;   // 3125 + 6 = 3131 (bucket padding)
constexpr int PERMN = NBLK * BM;                // 200384

// ---------------- init / diagnostic ----------------

__global__ void k_memset32(int* __restrict__ p, int v, int n) {
    int i = blockIdx.x * 256 + threadIdx.x;
    if (i < n) p[i] = v;
}

__global__ void k_report(float* __restrict__ outp, float v, int n) {
    int i = blockIdx.x * 256 + threadIdx.x;
    if (i < n) outp[i] = v;
}

// ---------------- graph preprocessing ----------------

__global__ void k_count_deg(const int* __restrict__ dst, int* __restrict__ deg) {
    int e = blockIdx.x * 256 + threadIdx.x;
    if (e < NE) atomicAdd(&deg[dst[e]], 1);
}

__global__ void k_scan_part(const int* __restrict__ deg, int* __restrict__ part) {
    __shared__ int s[256];
    int t = threadIdx.x, i = blockIdx.x * 256 + t;
    s[t] = (i < NN) ? deg[i] : 0;
    __syncthreads();
    for (int st = 128; st > 0; st >>= 1) {
        if (t < st) s[t] += s[t + st];
        __syncthreads();
    }
    if (t == 0) part[blockIdx.x] = s[0];
}

__global__ void k_scan_single(int* __restrict__ part, int nb) {
    __shared__ int s[1024];
    int t = threadIdx.x;
    int v0 = (t < nb) ? part[t] : 0;
    s[t] = v0;
    __syncthreads();
    for (int off = 1; off < 1024; off <<= 1) {
        int v = (t >= off) ? s[t - off] : 0;
        __syncthreads();
        s[t] += v;
        __syncthreads();
    }
    if (t < nb) part[t] = s[t] - v0;   // exclusive prefix of block sums
}

__global__ void k_scan_final(const int* __restrict__ deg, const int* __restrict__ part,
                             int* __restrict__ row_ptr, int* __restrict__ cursor) {
    __shared__ int s[256];
    int t = threadIdx.x, i = blockIdx.x * 256 + t;
    int v0 = (i < NN) ? deg[i] : 0;
    s[t] = v0;
    __syncthreads();
    for (int off = 1; off < 256; off <<= 1) {
        int v = (t >= off) ? s[t - off] : 0;
        __syncthreads();
        s[t] += v;
        __syncthreads();
    }
    if (i < NN) {
        int excl = s[t] - v0 + part[blockIdx.x];
        row_ptr[i] = excl;
        cursor[i]  = excl;
        if (i == NN - 1) row_ptr[NN] = excl + v0;
    }
}

__global__ void k_fill_csr(const int* __restrict__ src, const int* __restrict__ dst,
                           int* __restrict__ cursor, int* __restrict__ col) {
    int e = blockIdx.x * 256 + threadIdx.x;
    if (e < NE) {
        int d = dst[e];
        int slot = atomicAdd(&cursor[d], 1);
        col[slot] = src[e];
    }
}

__global__ void k_bucket_count(const int* __restrict__ deg, int* __restrict__ bcnt) {
    int i = blockIdx.x * 256 + threadIdx.x;
    if (i < NN) atomicAdd(&bcnt[min(deg[i], MAXD)], 1);
}

__global__ void k_bucket_scan(const int* __restrict__ bcnt, int* __restrict__ bpad) {
    if (threadIdx.x == 0 && blockIdx.x == 0) {
        int off = 0;
        for (int b = 0; b < 6; b++) {
            bpad[b] = off;
            off += ((bcnt[b] + BM - 1) / BM) * BM;
        }
        bpad[6] = off;
    }
}

__global__ void k_scatter(const int* __restrict__ deg, const int* __restrict__ bpad,
                          int* __restrict__ bcur, int* __restrict__ perm) {
    int i = blockIdx.x * 256 + threadIdx.x;
    if (i < NN) {
        int b = min(deg[i], MAXD);
        int pos = atomicAdd(&bcur[b], 1);
        perm[bpad[b] + pos] = i;
    }
}

// ---------------- layer-2a: plain neighbor-sum aggregate ----------------

// m2[i] = sum_{j->i} h[j], h has 128 cols.  4 nodes per 256-block.
__global__ void k_aggregate128(const float* __restrict__ hin, const int* __restrict__ row_ptr,
                               const int* __restrict__ col, float* __restrict__ msg) {
    int node = blockIdx.x * 4 + (threadIdx.x >> 6);
    int lane = threadIdx.x & 63;
    int s = row_ptr[node], e = row_ptr[node + 1];
    float2 acc = make_float2(0.f, 0.f);
    for (int p = s; p < e; p++) {
        const float2 v = *(const float2*)(hin + (size_t)col[p] * 128 + lane * 2);
        acc.x += v.x; acc.y += v.y;
    }
    *(float2*)(msg + (size_t)node * 128 + lane * 2) = acc;
}

// ---------------- fused aggregate + transform (gather mode) ----------------

// out[i] = [sum_{j->i} hin[j], hin[i]] @ [Wl[d]; Wr[d]] + bl[d], d = bucket(i).
// Input features split across hin0 (C0 cols) / hin1 (C1 cols); CIN = C0+C1.
// C0, C1 multiples of 32, so a 4-wide slice and its +16 partner never straddle.
// POOL_FUSE: no h store; rows atomically accumulated into pool[batch[node]].
// Epilogue always banks this chunk's Wf contribution into per-node logits.
template <int C0, int C1, int COUT, bool POOL_FUSE>
__launch_bounds__(256)
__global__ void k_transform(const float* __restrict__ hin0, const float* __restrict__ hin1,
                            const int* __restrict__ row_ptr, const int* __restrict__ col,
                            const float* __restrict__ Wl, const float* __restrict__ bl,
                            const float* __restrict__ Wr, const float* __restrict__ Wf,
                            const int* __restrict__ perm, const int* __restrict__ deg,
                            const int* __restrict__ batch,
                            float* __restrict__ out0, float* __restrict__ pool,
                            float* __restrict__ logits, int wf_off) {
    constexpr int CIN = C0 + C1;
    constexpr int K2  = 2 * CIN;
    __shared__ float As[KT][BM];
    __shared__ float Bs[KT][BN];
    __shared__ int rowid[BM];

    const int t  = threadIdx.x;
    const int m0 = blockIdx.x * BM;
    const int n0 = blockIdx.y * BN;

    if (t < BM) rowid[t] = perm[m0 + t];
    __syncthreads();
    if (rowid[0] < 0) return;  // fully-padded block (uniform exit)

    const int d = min(deg[rowid[0]], MAXD);
    const float* WlB = Wl + (size_t)d * CIN * COUT;
    const float* WrB = Wr + (size_t)d * CIN * COUT;

    const int am = t & 63, aq = t >> 6;
    const int anode = rowid[am];
    int es = 0, ee = 0;
    if (anode >= 0) { es = row_ptr[anode]; ee = row_ptr[anode + 1]; }
    const int bn = (t & 31) * 4, bk = t >> 5;
    const int tx = t & 15, ty = t >> 4;

    float acc[4][8];
#pragma unroll
    for (int r = 0; r < 4; r++)
#pragma unroll
        for (int c = 0; c < 8; c++) acc[r][c] = 0.f;

    for (int k0 = 0; k0 < K2; k0 += KT) {
        // stage A: thread owns row `am`, slices at gk0 and gk0+16 (same 32-block)
        {
            const int gk0 = k0 + 4 * aq;
            float4 v0 = make_float4(0.f, 0.f, 0.f, 0.f);
            float4 v1 = make_float4(0.f, 0.f, 0.f, 0.f);
            if (gk0 < CIN) {  // msg half: gather+sum neighbors (empty loop -> 0)
                if (C1 == 0 || gk0 < C0) {
                    for (int p = es; p < ee; p++) {
                        const float* r = hin0 + (size_t)col[p] * C0 + gk0;
                        const float4 a = *(const float4*)r;
                        const float4 b = *(const float4*)(r + 16);
                        v0.x += a.x; v0.y += a.y; v0.z += a.z; v0.w += a.w;
                        v1.x += b.x; v1.y += b.y; v1.z += b.z; v1.w += b.w;
                    }
                } else {
                    const int e0 = gk0 - C0;
                    for (int p = es; p < ee; p++) {
                        const float* r = hin1 + (size_t)col[p] * C1 + e0;
                        const float4 a = *(const float4*)r;
                        const float4 b = *(const float4*)(r + 16);
                        v0.x += a.x; v0.y += a.y; v0.z += a.z; v0.w += a.w;
                        v1.x += b.x; v1.y += b.y; v1.z += b.z; v1.w += b.w;
                    }
                }
            } else if (anode >= 0) {  // root half
                const int e = gk0 - CIN;
                const float* r = (C1 == 0 || e < C0)
                                     ? hin0 + (size_t)anode * C0 + e
                                     : hin1 + (size_t)anode * C1 + (e - C0);
                v0 = *(const float4*)r;
                v1 = *(const float4*)(r + 16);
            }
            const int kk0 = 4 * aq, kk1 = kk0 + 16;
            As[kk0 + 0][am] = v0.x; As[kk0 + 1][am] = v0.y;
            As[kk0 + 2][am] = v0.z; As[kk0 + 3][am] = v0.w;
            As[kk1 + 0][am] = v1.x; As[kk1 + 1][am] = v1.y;
            As[kk1 + 2][am] = v1.z; As[kk1 + 3][am] = v1.w;
        }
        // stage B (weights)
#pragma unroll
        for (int j = 0; j < 4; j++) {
            int kk = bk + 8 * j;
            int gk = k0 + kk;
            const float* p = (gk < CIN) ? (WlB + (size_t)gk * COUT + n0 + bn)
                                        : (WrB + (size_t)(gk - CIN) * COUT + n0 + bn);
            *(float4*)&Bs[kk][bn] = *(const float4*)p;
        }
        __syncthreads();
#pragma unroll
        for (int k = 0; k < KT; k++) {
            const float4 a  = *(const float4*)&As[k][ty * 4];
            const float4 b0 = *(const float4*)&Bs[k][tx * 8];
            const float4 b1 = *(const float4*)&Bs[k][tx * 8 + 4];
            const float av[4] = {a.x, a.y, a.z, a.w};
            const float bv[8] = {b0.x, b0.y, b0.z, b0.w, b1.x, b1.y, b1.z, b1.w};
#pragma unroll
            for (int r = 0; r < 4; r++)
#pragma unroll
                for (int c = 0; c < 8; c++) acc[r][c] = fmaf(av[r], bv[c], acc[r][c]);
        }
        __syncthreads();
    }

    // epilogue
    float blv[8], w0[8], w1[8];
#pragma unroll
    for (int c = 0; c < 8; c++) {
        int n = n0 + tx * 8 + c;
        blv[c] = bl[d * COUT + n];
        w0[c]  = Wf[(size_t)(wf_off + n) * 2 + 0];
        w1[c]  = Wf[(size_t)(wf_off + n) * 2 + 1];
    }
#pragma unroll
    for (int r = 0; r < 4; r++) {
        int node = rowid[ty * 4 + r];
        float p0 = 0.f, p1 = 0.f;
        if (node >= 0) {
            float h[8];
#pragma unroll
            for (int c = 0; c < 8; c++) {
                h[c] = acc[r][c] + blv[c];
                p0 = fmaf(h[c], w0[c], p0);
                p1 = fmaf(h[c], w1[c], p1);
            }
            if constexpr (POOL_FUSE) {
                float* pr = pool + (size_t)batch[node] * 256 + n0 + tx * 8;
#pragma unroll
                for (int c = 0; c < 8; c++) atomicAdd(&pr[c], h[c]);
            } else {
                float* orow = out0 + (size_t)node * COUT + n0 + tx * 8;
                *(float4*)orow       = make_float4(h[0], h[1], h[2], h[3]);
                *(float4*)(orow + 4) = make_float4(h[4], h[5], h[6], h[7]);
            }
        }
#pragma unroll
        for (int s = 1; s < 16; s <<= 1) {
            p0 += __shfl_xor(p0, s, 64);
            p1 += __shfl_xor(p1, s, 64);
        }
        if (node >= 0 && tx == 0) {
            atomicAdd(&logits[(size_t)node * 2 + 0], p0);
            atomicAdd(&logits[(size_t)node * 2 + 1], p1);
        }
    }
}

// ---------------- layer-2b: full-width GEMM, in-place output ----------------

// h2 = [m2 | h1] @ [Wl; Wr] + bl, d-bucketed; K2 = 256, COUT = 256.
// ONE block owns 64 rows end-to-end (BN = 256, grid x only): all global reads
// of buf0/buf1 complete before the final K-loop barrier, then the epilogue
// writes the same rows in place (cols [0,128)->buf0, [128,256)->buf1).
// No cross-block row sharing => no read/write race (round-4 bug).
__launch_bounds__(256)
__global__ void k_gemm2b(float* __restrict__ buf0, float* __restrict__ buf1,
                         const float* __restrict__ Wl, const float* __restrict__ bl,
                         const float* __restrict__ Wr, const float* __restrict__ Wf,
                         const int* __restrict__ perm, const int* __restrict__ deg,
                         float* __restrict__ logits) {
    constexpr int K2 = 256, COUT = 256;
    __shared__ float As[KT][BM];     // 8 KB
    __shared__ float Bs[KT][COUT];   // 32 KB
    __shared__ int rowid[BM];

    const int t  = threadIdx.x;
    const int m0 = blockIdx.x * BM;

    if (t < BM) rowid[t] = perm[m0 + t];
    __syncthreads();
    if (rowid[0] < 0) return;

    const int d = min(deg[rowid[0]], MAXD);
    const float* WlB = Wl + (size_t)d * 128 * COUT;
    const float* WrB = Wr + (size_t)d * 128 * COUT;

    const int am = t & 63, aq = t >> 6;
    const int anode = rowid[am];
    const int bn = (t & 63) * 4, bk = t >> 6;   // B staging: 64 cols x 4 k-rows, 8 steps
    const int tx = t & 15, ty = t >> 4;

    float acc[4][16];
#pragma unroll
    for (int r = 0; r < 4; r++)
#pragma unroll
        for (int c = 0; c < 16; c++) acc[r][c] = 0.f;

    for (int k0 = 0; k0 < K2; k0 += KT) {
        // stage A (own rows only; slices at 4*aq and 4*aq+16 never straddle 128)
        {
            const int gk0 = k0 + 4 * aq;
            float4 v0 = make_float4(0.f, 0.f, 0.f, 0.f);
            float4 v1 = make_float4(0.f, 0.f, 0.f, 0.f);
            if (anode >= 0) {
                const float* r = (gk0 < 128) ? buf0 + (size_t)anode * 128 + gk0
                                             : buf1 + (size_t)anode * 128 + (gk0 - 128);
                v0 = *(const float4*)r;
                v1 = *(const float4*)(r + 16);
            }
            const int kk0 = 4 * aq, kk1 = kk0 + 16;
            As[kk0 + 0][am] = v0.x; As[kk0 + 1][am] = v0.y;
            As[kk0 + 2][am] = v0.z; As[kk0 + 3][am] = v0.w;
            As[kk1 + 0][am] = v1.x; As[kk1 + 1][am] = v1.y;
            As[kk1 + 2][am] = v1.z; As[kk1 + 3][am] = v1.w;
        }
        // stage B (weights, full 256-wide)
#pragma unroll
        for (int j = 0; j < 8; j++) {
            int kk = bk + 4 * j;
            int gk = k0 + kk;
            const float* p = (gk < 128) ? (WlB + (size_t)gk * COUT + bn)
                                        : (WrB + (size_t)(gk - 128) * COUT + bn);
            *(float4*)&Bs[kk][bn] = *(const float4*)p;
        }
        __syncthreads();
#pragma unroll
        for (int k = 0; k < KT; k++) {
            const float4 a  = *(const float4*)&As[k][ty * 4];
            const float av[4] = {a.x, a.y, a.z, a.w};
            float bv[16];
#pragma unroll
            for (int q = 0; q < 4; q++) {
                const float4 b = *(const float4*)&Bs[k][tx * 16 + 4 * q];
                bv[4 * q + 0] = b.x; bv[4 * q + 1] = b.y;
                bv[4 * q + 2] = b.z; bv[4 * q + 3] = b.w;
            }
#pragma unroll
            for (int r = 0; r < 4; r++)
#pragma unroll
                for (int c = 0; c < 16; c++) acc[r][c] = fmaf(av[r], bv[c], acc[r][c]);
        }
        __syncthreads();
    }

    // epilogue: n = tx*16 + c; tx<8 -> buf0 cols [0,128), tx>=8 -> buf1
    float blv[16], w0[16], w1[16];
#pragma unroll
    for (int c = 0; c < 16; c++) {
        int n = tx * 16 + c;
        blv[c] = bl[d * COUT + n];
        w0[c]  = Wf[(size_t)(256 + n) * 2 + 0];
        w1[c]  = Wf[(size_t)(256 + n) * 2 + 1];
    }
#pragma unroll
    for (int r = 0; r < 4; r++) {
        int node = rowid[ty * 4 + r];
        float p0 = 0.f, p1 = 0.f;
        if (node >= 0) {
            float h[16];
#pragma unroll
            for (int c = 0; c < 16; c++) {
                h[c] = acc[r][c] + blv[c];
                p0 = fmaf(h[c], w0[c], p0);
                p1 = fmaf(h[c], w1[c], p1);
            }
            float* ob = (tx < 8) ? buf0 + (size_t)node * 128 + tx * 16
                                 : buf1 + (size_t)node * 128 + (tx - 8) * 16;
#pragma unroll
            for (int q = 0; q < 4; q++)
                *(float4*)(ob + 4 * q) =
                    make_float4(h[4 * q], h[4 * q + 1], h[4 * q + 2], h[4 * q + 3]);
        }
#pragma unroll
        for (int s = 1; s < 16; s <<= 1) {
            p0 += __shfl_xor(p0, s, 64);
            p1 += __shfl_xor(p1, s, 64);
        }
        if (node >= 0 && tx == 0) {
            atomicAdd(&logits[(size_t)node * 2 + 0], p0);
            atomicAdd(&logits[(size_t)node * 2 + 1], p1);
        }
    }
}

// ---------------- pooling / output ----------------

__global__ void k_pool_logits(const float* __restrict__ pool, const float* __restrict__ Wf,
                              const float* __restrict__ bf, float* __restrict__ pl) {
    int g = blockIdx.x * 4 + (threadIdx.x >> 6);
    int lane = threadIdx.x & 63;
    const float* pr = pool + (size_t)g * 256;
    float p0 = 0.f, p1 = 0.f;
#pragma unroll
    for (int j = 0; j < 4; j++) {
        int k = lane + 64 * j;
        float v = pr[k];
        p0 = fmaf(v, Wf[(size_t)(768 + k) * 2 + 0], p0);
        p1 = fmaf(v, Wf[(size_t)(768 + k) * 2 + 1], p1);
    }
#pragma unroll
    for (int s = 1; s < 64; s <<= 1) {
        p0 += __shfl_xor(p0, s, 64);
        p1 += __shfl_xor(p1, s, 64);
    }
    if (lane == 0) {
        pl[(size_t)g * 2 + 0] = p0 + bf[0];
        pl[(size_t)g * 2 + 1] = p1 + bf[1];
    }
}

__global__ void k_final(const float* __restrict__ logits, const float* __restrict__ pl,
                        const int* __restrict__ batch, float* __restrict__ outp) {
    int i = blockIdx.x * 256 + threadIdx.x;
    if (i < NN) {
        int g = batch[i];
        float l0 = logits[(size_t)i * 2 + 0] + pl[(size_t)g * 2 + 0];
        float l1 = logits[(size_t)i * 2 + 1] + pl[(size_t)g * 2 + 1];
        float m = fmaxf(l0, l1);
        float e0 = expf(l0 - m), e1 = expf(l1 - m);
        float inv = 1.f / (e0 + e1);
        outp[(size_t)i * 2 + 0] = e0 * inv;
        outp[(size_t)i * 2 + 1] = e1 * inv;
    }
}

}  // namespace

extern "C" void kernel_launch(void* const* d_in, const int* in_sizes, int n_in,
                              void* d_out, int out_size, void* d_ws, size_t ws_size,
                              hipStream_t stream) {
    const float* x     = (const float*)d_in[0];
    const int*   ei    = (const int*)d_in[1];
    const int*   batch = (const int*)d_in[2];
    const float* Wl0 = (const float*)d_in[3];  const float* bl0 = (const float*)d_in[4];
    const float* Wr0 = (const float*)d_in[5];
    const float* Wl1 = (const float*)d_in[6];  const float* bl1 = (const float*)d_in[7];
    const float* Wr1 = (const float*)d_in[8];
    const float* Wl2 = (const float*)d_in[9];  const float* bl2 = (const float*)d_in[10];
    const float* Wr2 = (const float*)d_in[11];
    const float* Wl3 = (const float*)d_in[12]; const float* bl3 = (const float*)d_in[13];
    const float* Wr3 = (const float*)d_in[14];
    const float* Wf  = (const float*)d_in[15]; const float* bf  = (const float*)d_in[16];
    const int* src = ei;
    const int* dst = ei + NE;
    float* outp = (float*)d_out;
    (void)in_sizes; (void)n_in;

    // workspace bump allocator (256B aligned).  Total ≈ 218 MB (ws is 256 MB).
    char* w = (char*)d_ws;
    auto alloc = [&](size_t bytes) -> void* {
        void* p = (void*)w;
        w += (bytes + 255) & ~(size_t)255;
        return p;
    };
    // zero-init region (contiguous): deg .. pool
    int*   deg    = (int*)alloc((size_t)NN * 4);
    int*   bcnt   = (int*)alloc(32);
    int*   bcur   = (int*)alloc(32);
    float* logits = (float*)alloc((size_t)NN * 2 * 4);
    float* pool   = (float*)alloc((size_t)NG * 256 * 4);
    size_t zero_words = (size_t)(w - (char*)deg) / 4;
    // fully-written-by-kernel regions
    int*   bpad    = (int*)alloc(32);
    int*   perm    = (int*)alloc((size_t)PERMN * 4);      // filled with -1
    int*   row_ptr = (int*)alloc((size_t)(NN + 1) * 4);
    int*   cursor  = (int*)alloc((size_t)NN * 4);
    int*   col     = (int*)alloc((size_t)NE * 4);
    int*   part    = (int*)alloc(1024 * 4);
    float* pl      = (float*)alloc((size_t)NG * 2 * 4);
    float* bufA    = (float*)alloc((size_t)NN * 128 * 4);  // h0 -> m2 -> h2[:,0:128)
    float* bufB    = (float*)alloc((size_t)NN * 128 * 4);  // h1 -> h2[:,128:256)

    size_t required = (size_t)(w - (char*)d_ws);
    if (required > ws_size) {
        // Diagnostic: report actual ws_size (in MB) through the output.
        k_report<<<(out_size + 255) / 256, 256, 0, stream>>>(
            outp, (float)(double)(ws_size >> 20), out_size);
        return;
    }

    dim3 b256(256);
    k_memset32<<<(int)((zero_words + 255) / 256), b256, 0, stream>>>((int*)deg, 0, (int)zero_words);
    k_memset32<<<(PERMN + 255) / 256, b256, 0, stream>>>(perm, -1, PERMN);

    k_count_deg<<<NE / 256, b256, 0, stream>>>(dst, deg);
    k_scan_part<<<782, b256, 0, stream>>>(deg, part);
    k_scan_single<<<1, 1024, 0, stream>>>(part, 782);
    k_scan_final<<<782, b256, 0, stream>>>(deg, part, row_ptr, cursor);
    k_fill_csr<<<NE / 256, b256, 0, stream>>>(src, dst, cursor, col);
    k_bucket_count<<<782, b256, 0, stream>>>(deg, bcnt);
    k_bucket_scan<<<1, 64, 0, stream>>>(bcnt, bpad);
    k_scatter<<<782, b256, 0, stream>>>(deg, bpad, bcur, perm);

    // Layer 0: in=x(64) -> h0=bufA(128)
    k_transform<64, 0, 128, false><<<dim3(NBLK, 1), b256, 0, stream>>>(
        x, nullptr, row_ptr, col, Wl0, bl0, Wr0, Wf, perm, deg, nullptr,
        bufA, nullptr, logits, 0);
    // Layer 1: in=bufA(128) -> h1=bufB(128)          [h0 dead after this]
    k_transform<128, 0, 128, false><<<dim3(NBLK, 1), b256, 0, stream>>>(
        bufA, nullptr, row_ptr, col, Wl1, bl1, Wr1, Wf, perm, deg, nullptr,
        bufB, nullptr, logits, 128);
    // Layer 2a: m2 = gather-sum(h1) -> bufA
    k_aggregate128<<<NN / 4, b256, 0, stream>>>(bufB, row_ptr, col, bufA);
    // Layer 2b: h2 = [m2|h1] @ [Wl2;Wr2] + bl2, in place -> [bufA|bufB]
    //           (full-width blocks: one block owns its 64 rows -> race-free)
    k_gemm2b<<<dim3(NBLK), b256, 0, stream>>>(
        bufA, bufB, Wl2, bl2, Wr2, Wf, perm, deg, logits);
    // Layer 3: in=[bufA|bufB](256) -> logits chunk + pool (h3 never stored)
    k_transform<128, 128, 256, true><<<dim3(NBLK, 2), b256, 0, stream>>>(
        bufA, bufB, row_ptr, col, Wl3, bl3, Wr3, Wf, perm, deg, batch,
        nullptr, pool, logits, 512);

    k_pool_logits<<<NG / 4, b256, 0, stream>>>(pool, Wf, bf, pl);
    k_final<<<782, b256, 0, stream>>>(logits, pl, batch, outp);
}

// Round 6
// 4618.541 us; speedup vs baseline: 1.1817x; 1.1817x over previous
//
#include <hip/hip_runtime.h>
#include <cstdint>
#include <cstddef>

namespace {

constexpr int NN   = 200000;   // nodes
constexpr int NE   = 800000;   // edges
constexpr int NG   = 4096;     // graphs
constexpr int MAXD = 5;

constexpr int BM = 64;
constexpr int BN = 128;
constexpr int KT = 32;
constexpr int NBLK  = (NN + BM - 1) / BM + 6;   // 3125 + 6 = 3131 (bucket padding)
constexpr int PERMN = NBLK * BM;                // 200384

// ---------------- init / diagnostic ----------------

__global__ void k_memset32(int* __restrict__ p, int v, int n) {
    int i = blockIdx.x * 256 + threadIdx.x;
    if (i < n) p[i] = v;
}

__global__ void k_report(float* __restrict__ outp, float v, int n) {
    int i = blockIdx.x * 256 + threadIdx.x;
    if (i < n) outp[i] = v;
}

// ---------------- graph preprocessing ----------------

__global__ void k_count_deg(const int* __restrict__ dst, int* __restrict__ deg) {
    int e = blockIdx.x * 256 + threadIdx.x;
    if (e < NE) atomicAdd(&deg[dst[e]], 1);
}

__global__ void k_scan_part(const int* __restrict__ deg, int* __restrict__ part) {
    __shared__ int s[256];
    int t = threadIdx.x, i = blockIdx.x * 256 + t;
    s[t] = (i < NN) ? deg[i] : 0;
    __syncthreads();
    for (int st = 128; st > 0; st >>= 1) {
        if (t < st) s[t] += s[t + st];
        __syncthreads();
    }
    if (t == 0) part[blockIdx.x] = s[0];
}

__global__ void k_scan_single(int* __restrict__ part, int nb) {
    __shared__ int s[1024];
    int t = threadIdx.x;
    int v0 = (t < nb) ? part[t] : 0;
    s[t] = v0;
    __syncthreads();
    for (int off = 1; off < 1024; off <<= 1) {
        int v = (t >= off) ? s[t - off] : 0;
        __syncthreads();
        s[t] += v;
        __syncthreads();
    }
    if (t < nb) part[t] = s[t] - v0;   // exclusive prefix of block sums
}

__global__ void k_scan_final(const int* __restrict__ deg, const int* __restrict__ part,
                             int* __restrict__ row_ptr, int* __restrict__ cursor) {
    __shared__ int s[256];
    int t = threadIdx.x, i = blockIdx.x * 256 + t;
    int v0 = (i < NN) ? deg[i] : 0;
    s[t] = v0;
    __syncthreads();
    for (int off = 1; off < 256; off <<= 1) {
        int v = (t >= off) ? s[t - off] : 0;
        __syncthreads();
        s[t] += v;
        __syncthreads();
    }
    if (i < NN) {
        int excl = s[t] - v0 + part[blockIdx.x];
        row_ptr[i] = excl;
        cursor[i]  = excl;
        if (i == NN - 1) row_ptr[NN] = excl + v0;
    }
}

__global__ void k_fill_csr(const int* __restrict__ src, const int* __restrict__ dst,
                           int* __restrict__ cursor, int* __restrict__ col) {
    int e = blockIdx.x * 256 + threadIdx.x;
    if (e < NE) {
        int d = dst[e];
        int slot = atomicAdd(&cursor[d], 1);
        col[slot] = src[e];
    }
}

__global__ void k_bucket_count(const int* __restrict__ deg, int* __restrict__ bcnt) {
    int i = blockIdx.x * 256 + threadIdx.x;
    if (i < NN) atomicAdd(&bcnt[min(deg[i], MAXD)], 1);
}

__global__ void k_bucket_scan(const int* __restrict__ bcnt, int* __restrict__ bpad) {
    if (threadIdx.x == 0 && blockIdx.x == 0) {
        int off = 0;
        for (int b = 0; b < 6; b++) {
            bpad[b] = off;
            off += ((bcnt[b] + BM - 1) / BM) * BM;
        }
        bpad[6] = off;
    }
}

__global__ void k_scatter(const int* __restrict__ deg, const int* __restrict__ bpad,
                          int* __restrict__ bcur, int* __restrict__ perm) {
    int i = blockIdx.x * 256 + threadIdx.x;
    if (i < NN) {
        int b = min(deg[i], MAXD);
        int pos = atomicAdd(&bcur[b], 1);
        perm[bpad[b] + pos] = i;
    }
}

// ---------------- layer-2a: plain neighbor-sum aggregate ----------------

__global__ void k_aggregate128(const float* __restrict__ hin, const int* __restrict__ row_ptr,
                               const int* __restrict__ col, float* __restrict__ msg) {
    int node = blockIdx.x * 4 + (threadIdx.x >> 6);
    int lane = threadIdx.x & 63;
    int s = row_ptr[node], e = row_ptr[node + 1];
    float2 acc = make_float2(0.f, 0.f);
    for (int p = s; p < e; p++) {
        const float2 v = *(const float2*)(hin + (size_t)col[p] * 128 + lane * 2);
        acc.x += v.x; acc.y += v.y;
    }
    *(float2*)(msg + (size_t)node * 128 + lane * 2) = acc;
}

// ---------------- fused aggregate + transform (register-gather) ----------------

// out[i] = [sum_{j->i} hin[j], hin[i]] @ [Wl[d]; Wr[d]] + bl[d], d = bucket(i).
// The neighbor gather is hoisted OUT of the K-loop: each staging thread owns
// fixed col-slices (4*aq and 16+4*aq of each 32-col window) and walks the
// edge list ONCE, accumulating all CIN/4 owned floats into mreg[].  The
// K-loop's msg staging is then pure reg->LDS (no global latency between
// barriers).  Root-half tiles load the thread's own row directly (coalesced).
// Lane B-columns are two chunks {4tx, 64+4tx} (2-way LDS bank pattern = free).
// POOL_FUSE: no h store; rows atomically accumulated into pool[batch[node]].
// Epilogue always banks this chunk's Wf contribution into per-node logits.
template <int C0, int C1, int COUT, bool POOL_FUSE>
__launch_bounds__(256)
__global__ void k_transform(const float* __restrict__ hin0, const float* __restrict__ hin1,
                            const int* __restrict__ row_ptr, const int* __restrict__ col,
                            const float* __restrict__ Wl, const float* __restrict__ bl,
                            const float* __restrict__ Wr, const float* __restrict__ Wf,
                            const int* __restrict__ perm, const int* __restrict__ deg,
                            const int* __restrict__ batch,
                            float* __restrict__ out0, float* __restrict__ pool,
                            float* __restrict__ logits, int wf_off) {
    constexpr int CIN = C0 + C1;
    constexpr int K2  = 2 * CIN;
    constexpr int NW0 = C0 / 32;    // msg windows served by hin0
    constexpr int NW  = CIN / 32;   // total msg windows (= msg K-tiles)
    __shared__ float As[KT][BM];
    __shared__ float Bs[KT][BN];
    __shared__ int rowid[BM];

    const int t  = threadIdx.x;
    const int m0 = blockIdx.x * BM;
    const int n0 = blockIdx.y * BN;

    if (t < BM) rowid[t] = perm[m0 + t];
    __syncthreads();
    if (rowid[0] < 0) return;  // fully-padded block (uniform exit)

    const int d = min(deg[rowid[0]], MAXD);
    const float* WlB = Wl + (size_t)d * CIN * COUT;
    const float* WrB = Wr + (size_t)d * CIN * COUT;

    const int am = t & 63, aq = t >> 6;
    const int anode = rowid[am];
    int es = 0, ee = 0;
    if (anode >= 0) { es = row_ptr[anode]; ee = row_ptr[anode + 1]; }
    const int bn = (t & 31) * 4, bk = t >> 5;
    const int tx = t & 15, ty = t >> 4;

    // ---- pre-gather: one edge-list walk fills all owned msg slices ----
    float mreg[8 * NW];
#pragma unroll
    for (int i = 0; i < 8 * NW; i++) mreg[i] = 0.f;
    for (int p = es; p < ee; p++) {
        const int j = col[p];
        const float* r0 = hin0 + (size_t)j * C0 + 4 * aq;
#pragma unroll
        for (int ti = 0; ti < NW0; ti++) {
            const float4 a = *(const float4*)(r0 + 32 * ti);
            const float4 b = *(const float4*)(r0 + 32 * ti + 16);
            mreg[8*ti+0] += a.x; mreg[8*ti+1] += a.y;
            mreg[8*ti+2] += a.z; mreg[8*ti+3] += a.w;
            mreg[8*ti+4] += b.x; mreg[8*ti+5] += b.y;
            mreg[8*ti+6] += b.z; mreg[8*ti+7] += b.w;
        }
        if constexpr (C1 > 0) {
            const float* r1 = hin1 + (size_t)j * C1 + 4 * aq;
#pragma unroll
            for (int ti = NW0; ti < NW; ti++) {
                const float4 a = *(const float4*)(r1 + 32 * (ti - NW0));
                const float4 b = *(const float4*)(r1 + 32 * (ti - NW0) + 16);
                mreg[8*ti+0] += a.x; mreg[8*ti+1] += a.y;
                mreg[8*ti+2] += a.z; mreg[8*ti+3] += a.w;
                mreg[8*ti+4] += b.x; mreg[8*ti+5] += b.y;
                mreg[8*ti+6] += b.z; mreg[8*ti+7] += b.w;
            }
        }
    }

    float acc[4][8];
#pragma unroll
    for (int r = 0; r < 4; r++)
#pragma unroll
        for (int c = 0; c < 8; c++) acc[r][c] = 0.f;

    for (int ti = 0; ti < 2 * NW; ti++) {
        const int k0 = ti * KT;
        // stage A: msg tiles from mreg; root tiles from own row
        {
            float4 v0, v1;
            if (ti < NW) {
                v0 = make_float4(mreg[8*ti+0], mreg[8*ti+1], mreg[8*ti+2], mreg[8*ti+3]);
                v1 = make_float4(mreg[8*ti+4], mreg[8*ti+5], mreg[8*ti+6], mreg[8*ti+7]);
            } else {
                v0 = make_float4(0.f, 0.f, 0.f, 0.f);
                v1 = v0;
                if (anode >= 0) {
                    const int e = k0 - CIN + 4 * aq;
                    const float* r = (C1 == 0 || e < C0)
                                         ? hin0 + (size_t)anode * C0 + e
                                         : hin1 + (size_t)anode * C1 + (e - C0);
                    v0 = *(const float4*)r;
                    v1 = *(const float4*)(r + 16);
                }
            }
            const int kk0 = 4 * aq, kk1 = kk0 + 16;
            As[kk0 + 0][am] = v0.x; As[kk0 + 1][am] = v0.y;
            As[kk0 + 2][am] = v0.z; As[kk0 + 3][am] = v0.w;
            As[kk1 + 0][am] = v1.x; As[kk1 + 1][am] = v1.y;
            As[kk1 + 2][am] = v1.z; As[kk1 + 3][am] = v1.w;
        }
        // stage B (weights)
#pragma unroll
        for (int j = 0; j < 4; j++) {
            int kk = bk + 8 * j;
            int gk = k0 + kk;
            const float* p = (gk < CIN) ? (WlB + (size_t)gk * COUT + n0 + bn)
                                        : (WrB + (size_t)(gk - CIN) * COUT + n0 + bn);
            *(float4*)&Bs[kk][bn] = *(const float4*)p;
        }
        __syncthreads();
#pragma unroll
        for (int k = 0; k < KT; k++) {
            const float4 a  = *(const float4*)&As[k][ty * 4];
            const float4 b0 = *(const float4*)&Bs[k][4 * tx];        // chunk 0
            const float4 b1 = *(const float4*)&Bs[k][64 + 4 * tx];   // chunk 1
            const float av[4] = {a.x, a.y, a.z, a.w};
            const float bv[8] = {b0.x, b0.y, b0.z, b0.w, b1.x, b1.y, b1.z, b1.w};
#pragma unroll
            for (int r = 0; r < 4; r++)
#pragma unroll
                for (int c = 0; c < 8; c++) acc[r][c] = fmaf(av[r], bv[c], acc[r][c]);
        }
        __syncthreads();
    }

    // epilogue: lane cols are n0 + {4tx..4tx+3} (c<4) and n0+64+{4tx..} (c>=4)
    float blv[8], w0[8], w1[8];
#pragma unroll
    for (int c = 0; c < 8; c++) {
        const int n = n0 + ((c < 4) ? (4 * tx + c) : (64 + 4 * tx + c - 4));
        blv[c] = bl[d * COUT + n];
        w0[c]  = Wf[(size_t)(wf_off + n) * 2 + 0];
        w1[c]  = Wf[(size_t)(wf_off + n) * 2 + 1];
    }
#pragma unroll
    for (int r = 0; r < 4; r++) {
        const int node = rowid[ty * 4 + r];
        float p0 = 0.f, p1 = 0.f;
        if (node >= 0) {
            float h[8];
#pragma unroll
            for (int c = 0; c < 8; c++) {
                h[c] = acc[r][c] + blv[c];
                p0 = fmaf(h[c], w0[c], p0);
                p1 = fmaf(h[c], w1[c], p1);
            }
            if constexpr (POOL_FUSE) {
                float* pr = pool + (size_t)batch[node] * 256 + n0;
#pragma unroll
                for (int c = 0; c < 8; c++) {
                    const int n = (c < 4) ? (4 * tx + c) : (64 + 4 * tx + c - 4);
                    atomicAdd(&pr[n], h[c]);
                }
            } else {
                float* orow = out0 + (size_t)node * COUT + n0;
                *(float4*)(orow + 4 * tx)      = make_float4(h[0], h[1], h[2], h[3]);
                *(float4*)(orow + 64 + 4 * tx) = make_float4(h[4], h[5], h[6], h[7]);
            }
        }
#pragma unroll
        for (int s = 1; s < 16; s <<= 1) {
            p0 += __shfl_xor(p0, s, 64);
            p1 += __shfl_xor(p1, s, 64);
        }
        if (node >= 0 && tx == 0) {
            atomicAdd(&logits[(size_t)node * 2 + 0], p0);
            atomicAdd(&logits[(size_t)node * 2 + 1], p1);
        }
    }
}

// ---------------- layer-2b: full-width GEMM, in-place output ----------------

// h2 = [m2 | h1] @ [Wl; Wr] + bl, d-bucketed; K2 = 256, COUT = 256.
// ONE block owns 64 rows end-to-end (race-free in-place).  Lane cols are four
// chunks {4tx, 64+4tx, 128+4tx, 192+4tx} (2-way LDS bank pattern).
__launch_bounds__(256)
__global__ void k_gemm2b(float* __restrict__ buf0, float* __restrict__ buf1,
                         const float* __restrict__ Wl, const float* __restrict__ bl,
                         const float* __restrict__ Wr, const float* __restrict__ Wf,
                         const int* __restrict__ perm, const int* __restrict__ deg,
                         float* __restrict__ logits) {
    constexpr int K2 = 256, COUT = 256;
    __shared__ float As[KT][BM];     // 8 KB
    __shared__ float Bs[KT][COUT];   // 32 KB
    __shared__ int rowid[BM];

    const int t  = threadIdx.x;
    const int m0 = blockIdx.x * BM;

    if (t < BM) rowid[t] = perm[m0 + t];
    __syncthreads();
    if (rowid[0] < 0) return;

    const int d = min(deg[rowid[0]], MAXD);
    const float* WlB = Wl + (size_t)d * 128 * COUT;
    const float* WrB = Wr + (size_t)d * 128 * COUT;

    const int am = t & 63, aq = t >> 6;
    const int anode = rowid[am];
    const int bn = (t & 63) * 4, bk = t >> 6;
    const int tx = t & 15, ty = t >> 4;

    float acc[4][16];
#pragma unroll
    for (int r = 0; r < 4; r++)
#pragma unroll
        for (int c = 0; c < 16; c++) acc[r][c] = 0.f;

    for (int k0 = 0; k0 < K2; k0 += KT) {
        {
            const int gk0 = k0 + 4 * aq;
            float4 v0 = make_float4(0.f, 0.f, 0.f, 0.f);
            float4 v1 = v0;
            if (anode >= 0) {
                const float* r = (gk0 < 128) ? buf0 + (size_t)anode * 128 + gk0
                                             : buf1 + (size_t)anode * 128 + (gk0 - 128);
                v0 = *(const float4*)r;
                v1 = *(const float4*)(r + 16);
            }
            const int kk0 = 4 * aq, kk1 = kk0 + 16;
            As[kk0 + 0][am] = v0.x; As[kk0 + 1][am] = v0.y;
            As[kk0 + 2][am] = v0.z; As[kk0 + 3][am] = v0.w;
            As[kk1 + 0][am] = v1.x; As[kk1 + 1][am] = v1.y;
            As[kk1 + 2][am] = v1.z; As[kk1 + 3][am] = v1.w;
        }
#pragma unroll
        for (int j = 0; j < 8; j++) {
            int kk = bk + 4 * j;
            int gk = k0 + kk;
            const float* p = (gk < 128) ? (WlB + (size_t)gk * COUT + bn)
                                        : (WrB + (size_t)(gk - 128) * COUT + bn);
            *(float4*)&Bs[kk][bn] = *(const float4*)p;
        }
        __syncthreads();
#pragma unroll
        for (int k = 0; k < KT; k++) {
            const float4 a = *(const float4*)&As[k][ty * 4];
            const float av[4] = {a.x, a.y, a.z, a.w};
            float bv[16];
#pragma unroll
            for (int q = 0; q < 4; q++) {
                const float4 b = *(const float4*)&Bs[k][64 * q + 4 * tx];
                bv[4 * q + 0] = b.x; bv[4 * q + 1] = b.y;
                bv[4 * q + 2] = b.z; bv[4 * q + 3] = b.w;
            }
#pragma unroll
            for (int r = 0; r < 4; r++)
#pragma unroll
                for (int c = 0; c < 16; c++) acc[r][c] = fmaf(av[r], bv[c], acc[r][c]);
        }
        __syncthreads();
    }

    // epilogue: n = 64*(c>>2) + 4*tx + (c&3); q<2 -> buf0, q>=2 -> buf1
    float blv[16], w0[16], w1[16];
#pragma unroll
    for (int c = 0; c < 16; c++) {
        const int n = 64 * (c >> 2) + 4 * tx + (c & 3);
        blv[c] = bl[d * COUT + n];
        w0[c]  = Wf[(size_t)(256 + n) * 2 + 0];
        w1[c]  = Wf[(size_t)(256 + n) * 2 + 1];
    }
#pragma unroll
    for (int r = 0; r < 4; r++) {
        const int node = rowid[ty * 4 + r];
        float p0 = 0.f, p1 = 0.f;
        if (node >= 0) {
            float h[16];
#pragma unroll
            for (int c = 0; c < 16; c++) {
                h[c] = acc[r][c] + blv[c];
                p0 = fmaf(h[c], w0[c], p0);
                p1 = fmaf(h[c], w1[c], p1);
            }
#pragma unroll
            for (int q = 0; q < 4; q++) {
                float* ob = (q < 2) ? buf0 + (size_t)node * 128 + 64 * q + 4 * tx
                                    : buf1 + (size_t)node * 128 + 64 * (q - 2) + 4 * tx;
                *(float4*)ob = make_float4(h[4*q], h[4*q+1], h[4*q+2], h[4*q+3]);
            }
        }
#pragma unroll
        for (int s = 1; s < 16; s <<= 1) {
            p0 += __shfl_xor(p0, s, 64);
            p1 += __shfl_xor(p1, s, 64);
        }
        if (node >= 0 && tx == 0) {
            atomicAdd(&logits[(size_t)node * 2 + 0], p0);
            atomicAdd(&logits[(size_t)node * 2 + 1], p1);
        }
    }
}

// ---------------- pooling / output ----------------

__global__ void k_pool_logits(const float* __restrict__ pool, const float* __restrict__ Wf,
                              const float* __restrict__ bf, float* __restrict__ pl) {
    int g = blockIdx.x * 4 + (threadIdx.x >> 6);
    int lane = threadIdx.x & 63;
    const float* pr = pool + (size_t)g * 256;
    float p0 = 0.f, p1 = 0.f;
#pragma unroll
    for (int j = 0; j < 4; j++) {
        int k = lane + 64 * j;
        float v = pr[k];
        p0 = fmaf(v, Wf[(size_t)(768 + k) * 2 + 0], p0);
        p1 = fmaf(v, Wf[(size_t)(768 + k) * 2 + 1], p1);
    }
#pragma unroll
    for (int s = 1; s < 64; s <<= 1) {
        p0 += __shfl_xor(p0, s, 64);
        p1 += __shfl_xor(p1, s, 64);
    }
    if (lane == 0) {
        pl[(size_t)g * 2 + 0] = p0 + bf[0];
        pl[(size_t)g * 2 + 1] = p1 + bf[1];
    }
}

__global__ void k_final(const float* __restrict__ logits, const float* __restrict__ pl,
                        const int* __restrict__ batch, float* __restrict__ outp) {
    int i = blockIdx.x * 256 + threadIdx.x;
    if (i < NN) {
        int g = batch[i];
        float l0 = logits[(size_t)i * 2 + 0] + pl[(size_t)g * 2 + 0];
        float l1 = logits[(size_t)i * 2 + 1] + pl[(size_t)g * 2 + 1];
        float m = fmaxf(l0, l1);
        float e0 = expf(l0 - m), e1 = expf(l1 - m);
        float inv = 1.f / (e0 + e1);
        outp[(size_t)i * 2 + 0] = e0 * inv;
        outp[(size_t)i * 2 + 1] = e1 * inv;
    }
}

}  // namespace

extern "C" void kernel_launch(void* const* d_in, const int* in_sizes, int n_in,
                              void* d_out, int out_size, void* d_ws, size_t ws_size,
                              hipStream_t stream) {
    const float* x     = (const float*)d_in[0];
    const int*   ei    = (const int*)d_in[1];
    const int*   batch = (const int*)d_in[2];
    const float* Wl0 = (const float*)d_in[3];  const float* bl0 = (const float*)d_in[4];
    const float* Wr0 = (const float*)d_in[5];
    const float* Wl1 = (const float*)d_in[6];  const float* bl1 = (const float*)d_in[7];
    const float* Wr1 = (const float*)d_in[8];
    const float* Wl2 = (const float*)d_in[9];  const float* bl2 = (const float*)d_in[10];
    const float* Wr2 = (const float*)d_in[11];
    const float* Wl3 = (const float*)d_in[12]; const float* bl3 = (const float*)d_in[13];
    const float* Wr3 = (const float*)d_in[14];
    const float* Wf  = (const float*)d_in[15]; const float* bf  = (const float*)d_in[16];
    const int* src = ei;
    const int* dst = ei + NE;
    float* outp = (float*)d_out;
    (void)in_sizes; (void)n_in;

    // workspace bump allocator (256B aligned).  Total ≈ 218 MB (ws is 256 MB).
    char* w = (char*)d_ws;
    auto alloc = [&](size_t bytes) -> void* {
        void* p = (void*)w;
        w += (bytes + 255) & ~(size_t)255;
        return p;
    };
    // zero-init region (contiguous): deg .. pool
    int*   deg    = (int*)alloc((size_t)NN * 4);
    int*   bcnt   = (int*)alloc(32);
    int*   bcur   = (int*)alloc(32);
    float* logits = (float*)alloc((size_t)NN * 2 * 4);
    float* pool   = (float*)alloc((size_t)NG * 256 * 4);
    size_t zero_words = (size_t)(w - (char*)deg) / 4;
    // fully-written-by-kernel regions
    int*   bpad    = (int*)alloc(32);
    int*   perm    = (int*)alloc((size_t)PERMN * 4);      // filled with -1
    int*   row_ptr = (int*)alloc((size_t)(NN + 1) * 4);
    int*   cursor  = (int*)alloc((size_t)NN * 4);
    int*   col     = (int*)alloc((size_t)NE * 4);
    int*   part    = (int*)alloc(1024 * 4);
    float* pl      = (float*)alloc((size_t)NG * 2 * 4);
    float* bufA    = (float*)alloc((size_t)NN * 128 * 4);  // h0 -> m2 -> h2[:,0:128)
    float* bufB    = (float*)alloc((size_t)NN * 128 * 4);  // h1 -> h2[:,128:256)

    size_t required = (size_t)(w - (char*)d_ws);
    if (required > ws_size) {
        k_report<<<(out_size + 255) / 256, 256, 0, stream>>>(
            outp, (float)(double)(ws_size >> 20), out_size);
        return;
    }

    dim3 b256(256);
    k_memset32<<<(int)((zero_words + 255) / 256), b256, 0, stream>>>((int*)deg, 0, (int)zero_words);
    k_memset32<<<(PERMN + 255) / 256, b256, 0, stream>>>(perm, -1, PERMN);

    k_count_deg<<<NE / 256, b256, 0, stream>>>(dst, deg);
    k_scan_part<<<782, b256, 0, stream>>>(deg, part);
    k_scan_single<<<1, 1024, 0, stream>>>(part, 782);
    k_scan_final<<<782, b256, 0, stream>>>(deg, part, row_ptr, cursor);
    k_fill_csr<<<NE / 256, b256, 0, stream>>>(src, dst, cursor, col);
    k_bucket_count<<<782, b256, 0, stream>>>(deg, bcnt);
    k_bucket_scan<<<1, 64, 0, stream>>>(bcnt, bpad);
    k_scatter<<<782, b256, 0, stream>>>(deg, bpad, bcur, perm);

    // Layer 0: in=x(64) -> h0=bufA(128)
    k_transform<64, 0, 128, false><<<dim3(NBLK, 1), b256, 0, stream>>>(
        x, nullptr, row_ptr, col, Wl0, bl0, Wr0, Wf, perm, deg, nullptr,
        bufA, nullptr, logits, 0);
    // Layer 1: in=bufA(128) -> h1=bufB(128)          [h0 dead after this]
    k_transform<128, 0, 128, false><<<dim3(NBLK, 1), b256, 0, stream>>>(
        bufA, nullptr, row_ptr, col, Wl1, bl1, Wr1, Wf, perm, deg, nullptr,
        bufB, nullptr, logits, 128);
    // Layer 2a: m2 = gather-sum(h1) -> bufA
    k_aggregate128<<<NN / 4, b256, 0, stream>>>(bufB, row_ptr, col, bufA);
    // Layer 2b: h2 = [m2|h1] @ [Wl2;Wr2] + bl2, in place -> [bufA|bufB]
    k_gemm2b<<<dim3(NBLK), b256, 0, stream>>>(
        bufA, bufB, Wl2, bl2, Wr2, Wf, perm, deg, logits);
    // Layer 3: in=[bufA|bufB](256) -> logits chunk + pool (h3 never stored)
    k_transform<128, 128, 256, true><<<dim3(NBLK, 2), b256, 0, stream>>>(
        bufA, bufB, row_ptr, col, Wl3, bl3, Wr3, Wf, perm, deg, batch,
        nullptr, pool, logits, 512);

    k_pool_logits<<<NG / 4, b256, 0, stream>>>(pool, Wf, bf, pl);
    k_final<<<782, b256, 0, stream>>>(logits, pl, batch, outp);
}